// Round 9
// baseline (354.274 us; speedup 1.0000x reference)
//
#include <hip/hip_runtime.h>
#include <hip/hip_bf16.h>

// PicoLlmAttention: split-bf16 (hi+lo) MFMA pipeline, fp32-accurate everywhere.
// Round 9: attn VALU diet (edge-tile masking, exp2 softmax, defer-max) +
//          reg-staged K/V prefetch; fused split prepass.
// B=2, S=2048, E=1024, H=16, KV=4, D=64, window read from device.
#define SS 2048
#define EE 1024
#define RMS_EPS 1.1920929e-07f

typedef short v8s __attribute__((ext_vector_type(8)));   // 8 bf16 (4 VGPR)
typedef float v4f __attribute__((ext_vector_type(4)));   // MFMA acc

#define MFMA16 __builtin_amdgcn_mfma_f32_16x16x32_bf16

__device__ __forceinline__ ushort f2bf(float f){
    union { __hip_bfloat16 b; ushort u; } c; c.b = __float2bfloat16(f); return c.u;
}
__device__ __forceinline__ float bf2f(ushort u){
    union { uint u; float f; } c; c.u = ((uint)u) << 16; return c.f;
}
// split 8 consecutive fp32 into hi/lo bf16 packs (hi+lo ~ 16+ mantissa bits)
__device__ __forceinline__ void split8(const float* p, uint4& H, uint4& L){
    float4 a = *(const float4*)p, b = *(const float4*)(p+4);
    float v[8] = {a.x,a.y,a.z,a.w,b.x,b.y,b.z,b.w};
    ushort hs[8], ls[8];
#pragma unroll
    for (int e=0;e<8;e++){
        ushort h = f2bf(v[e]);
        hs[e] = h;
        ls[e] = f2bf(v[e] - bf2f(h));
    }
    H = *(uint4*)hs; L = *(uint4*)ls;
}

// ---------------------------------------------------------------------------
// Fused prepass: split x, Wq, Wk, Wv, Wp into hi/lo bf16. One launch.
// Group ranges (8 elems/group): x 524288 | Wq 131072 | Wk 32768 | Wv 32768 | Wp 131072
// grid 3328 x 256 = 851968 groups exactly.
// ---------------------------------------------------------------------------
__global__ __launch_bounds__(256)
void split_all(const float* __restrict__ x,  const float* __restrict__ Wq,
               const float* __restrict__ Wk, const float* __restrict__ Wv,
               const float* __restrict__ Wp,
               ushort* __restrict__ xh,  ushort* __restrict__ xl,
               ushort* __restrict__ Wch, ushort* __restrict__ Wcl,
               ushort* __restrict__ Wph, ushort* __restrict__ Wpl)
{
    int i = blockIdx.x*256 + threadIdx.x;
    const float* s; ushort *dh, *dl; size_t off;
    if (i < 524288){                       // x
        s = x; dh = xh; dl = xl; off = (size_t)i*8;
    } else if (i < 655360){                // Wq -> Wc rows [0,1024)
        size_t j = i - 524288; s = Wq; dh = Wch; dl = Wcl; off = j*8;
    } else if (i < 688128){                // Wk -> Wc rows [1024,1280)
        size_t j = i - 655360; s = Wk; dh = Wch + (size_t)1024*EE; dl = Wcl + (size_t)1024*EE; off = j*8;
    } else if (i < 720896){                // Wv -> Wc rows [1280,1536)
        size_t j = i - 688128; s = Wv; dh = Wch + (size_t)1280*EE; dl = Wcl + (size_t)1280*EE; off = j*8;
    } else {                               // Wp
        size_t j = i - 720896; s = Wp; dh = Wph; dl = Wpl; off = j*8;
    }
    uint4 H, L;
    split8(s + off, H, L);
    *(uint4*)(dh + off) = H;
    *(uint4*)(dl + off) = L;
}

// ---------------------------------------------------------------------------
// QKV projection: split-bf16 MFMA GEMM 128(M s) x 64(N d, one head).
// nt<16: Q (RoPE+RMS), nt in [16,20): K (RoPE+RMS), nt in [20,24): V (gate+ve).
// PRE=true: stage from pre-split xh/xl and concat Wch/Wcl (row = nt*64+rr).
// grid (24, 32), block 256 (4 waves; wave w owns 32 M-rows)
// ---------------------------------------------------------------------------
template<bool PRE>
__global__ __launch_bounds__(256)
void qkv_kernel(const float* __restrict__ x, const float* __restrict__ ve,
                const float* __restrict__ Wq, const float* __restrict__ Wk,
                const float* __restrict__ Wv, const float* __restrict__ Wg,
                const ushort* __restrict__ xh, const ushort* __restrict__ xl,
                const ushort* __restrict__ Wch, const ushort* __restrict__ Wcl,
                const float* __restrict__ cosb, const float* __restrict__ sinb,
                ushort* __restrict__ qhb, ushort* __restrict__ qlb,
                ushort* __restrict__ khb, ushort* __restrict__ klb,
                ushort* __restrict__ vhT, ushort* __restrict__ vlT)
{
    __shared__ ushort Axh[128*64];   // 16 KB
    __shared__ ushort Axl[128*64];   // 16 KB
    __shared__ ushort Bwh[64*64];    //  8 KB
    __shared__ ushort Bwl[64*64];    //  8 KB
    const int t = threadIdx.x;
    const int lane = t & 63, w = t >> 6;
    const int g = lane >> 4, ln = lane & 15;
    const int nt = blockIdx.x, mt = blockIdx.y;
    const float* W;
    if (nt < 16)      W = Wq + (size_t)nt*64*EE;
    else if (nt < 20) W = Wk + (size_t)(nt-16)*64*EE;
    else              W = Wv + (size_t)(nt-20)*64*EE;
    const v4f vzero = {0.f,0.f,0.f,0.f};
    v4f acc[2][4];
#pragma unroll
    for (int m=0;m<2;m++)
#pragma unroll
        for (int j=0;j<4;j++) acc[m][j] = vzero;

    const int sr = t>>3, sc = t&7;
    for (int kt = 0; kt < EE; kt += 64){
#pragma unroll
        for (int p2=0;p2<4;p2++){
            int rr = sr + 32*p2;
            int off = rr*64 + ((sc ^ (rr&7))<<3);
            if (PRE){
                *(uint4*)&Axh[off] = *(const uint4*)(xh + (size_t)(mt*128+rr)*EE + kt + sc*8);
                *(uint4*)&Axl[off] = *(const uint4*)(xl + (size_t)(mt*128+rr)*EE + kt + sc*8);
            } else {
                uint4 H,L; split8(x + (size_t)(mt*128+rr)*EE + kt + sc*8, H, L);
                *(uint4*)&Axh[off] = H; *(uint4*)&Axl[off] = L;
            }
        }
#pragma unroll
        for (int p2=0;p2<2;p2++){
            int rr = sr + 32*p2;
            int off = rr*64 + ((sc ^ (rr&7))<<3);
            if (PRE){
                *(uint4*)&Bwh[off] = *(const uint4*)(Wch + (size_t)(nt*64+rr)*EE + kt + sc*8);
                *(uint4*)&Bwl[off] = *(const uint4*)(Wcl + (size_t)(nt*64+rr)*EE + kt + sc*8);
            } else {
                uint4 H,L; split8(W + (size_t)rr*EE + kt + sc*8, H, L);
                *(uint4*)&Bwh[off] = H; *(uint4*)&Bwl[off] = L;
            }
        }
        __syncthreads();
        v8s ah[2][2], al[2][2], bh[4][2], bl[4][2];
#pragma unroll
        for (int m=0;m<2;m++){
            int row = 32*w + 16*m + ln;
#pragma unroll
            for (int s=0;s<2;s++){
                int off = row*64 + (((4*s+g) ^ (row&7))<<3);
                ah[m][s] = *(v8s*)&Axh[off];
                al[m][s] = *(v8s*)&Axl[off];
            }
        }
#pragma unroll
        for (int j=0;j<4;j++){
            int row = 16*j + ln;
#pragma unroll
            for (int s=0;s<2;s++){
                int off = row*64 + (((4*s+g) ^ (row&7))<<3);
                bh[j][s] = *(v8s*)&Bwh[off];
                bl[j][s] = *(v8s*)&Bwl[off];
            }
        }
#pragma unroll
        for (int m=0;m<2;m++)
#pragma unroll
            for (int j=0;j<4;j++)
#pragma unroll
                for (int s=0;s<2;s++){
                    acc[m][j] = MFMA16(ah[m][s], bh[j][s], acc[m][j], 0,0,0);
                    acc[m][j] = MFMA16(ah[m][s], bl[j][s], acc[m][j], 0,0,0);
                    acc[m][j] = MFMA16(al[m][s], bh[j][s], acc[m][j], 0,0,0);
                }
        __syncthreads();
    }

    // epilogue: lane holds C cols d = {ln,16+ln,32+ln,48+ln}, rows s = 32w+16m+4g+r
#pragma unroll
    for (int m=0;m<2;m++){
#pragma unroll
        for (int r=0;r<4;r++){
            int srow = mt*128 + 32*w + 16*m + 4*g + r;
            int bb  = srow >> 11;
            int ss_ = srow & 2047;
            float v0 = acc[m][0][r], v1 = acc[m][1][r];
            float v2 = acc[m][2][r], v3 = acc[m][3][r];
            if (nt < 20){
                // RoPE + RMSNorm*1.2, split-bf16 store
                float c0 = cosb[ss_*32 + ln],      s0 = sinb[ss_*32 + ln];
                float c1 = cosb[ss_*32 + 16 + ln], s1 = sinb[ss_*32 + 16 + ln];
                float lo0 =  v0*c0 + v2*s0, hi0 = -v0*s0 + v2*c0;  // d=ln    / 32+ln
                float lo1 =  v1*c1 + v3*s1, hi1 = -v1*s1 + v3*c1;  // d=16+ln / 48+ln
                float ssq = lo0*lo0 + hi0*hi0 + lo1*lo1 + hi1*hi1;
                ssq += __shfl_xor(ssq, 1); ssq += __shfl_xor(ssq, 2);
                ssq += __shfl_xor(ssq, 4); ssq += __shfl_xor(ssq, 8);
                float rs = rsqrtf(ssq*(1.f/64.f) + RMS_EPS) * 1.2f;
                size_t base = (nt < 16) ? ((size_t)(bb*16 + nt)*SS + ss_)*64
                                        : ((size_t)(bb*4 + (nt-16))*SS + ss_)*64;
                ushort* dh = (nt < 16) ? (qhb + base) : (khb + base);
                ushort* dl = (nt < 16) ? (qlb + base) : (klb + base);
                float o0 = lo0*rs, o1 = lo1*rs, o2 = hi0*rs, o3 = hi1*rs;
                ushort h0 = f2bf(o0), h1 = f2bf(o1), h2 = f2bf(o2), h3 = f2bf(o3);
                dh[ln]    = h0; dl[ln]    = f2bf(o0 - bf2f(h0));
                dh[16+ln] = h1; dl[16+ln] = f2bf(o1 - bf2f(h1));
                dh[32+ln] = h2; dl[32+ln] = f2bf(o2 - bf2f(h2));
                dh[48+ln] = h3; dl[48+ln] = f2bf(o3 - bf2f(h3));
            } else {
                // V head: out = acc + gate*ve, split-bf16 transposed store
                int head = nt - 20;
                float gsum = 0.f;
                const float* xr = x + (size_t)srow * EE;
#pragma unroll
                for (int c = 0; c < 12; c++) gsum += xr[c] * Wg[head*12 + c];
                float gate = 3.f / (1.f + __expf(-gsum));
                const float* ver = ve + (size_t)srow*256 + head*64;
                size_t vbase = ((size_t)(bb*4 + head)*64)*SS + ss_;
                float dv[4] = {v0, v1, v2, v3};
#pragma unroll
                for (int j=0;j<4;j++){
                    int d = 16*j + ln;
                    float ov = dv[j] + gate*ver[d];
                    ushort hh = f2bf(ov);
                    vhT[vbase + (size_t)d*SS] = hh;
                    vlT[vbase + (size_t)d*SS] = f2bf(ov - bf2f(hh));
                }
            }
        }
    }
}

// ---------------------------------------------------------------------------
// Flash attention, split-bf16 QK^T and PV (3-term each); P stays in registers.
// Q direct from global; reg-staged K/V prefetch; edge-only masking; exp2
// softmax with defer-max.  32KB LDS -> 4 blocks/CU.
// grid (32 qtiles, 32 b*h), block 256 (4 waves; wave w owns q rows 16w..16w+15)
// ---------------------------------------------------------------------------
__global__ __launch_bounds__(256, 4)
void attn_kernel(const ushort* __restrict__ qhb, const ushort* __restrict__ qlb,
                 const ushort* __restrict__ khb, const ushort* __restrict__ klb,
                 const ushort* __restrict__ vhT, const ushort* __restrict__ vlT,
                 const int* __restrict__ amask, const int* __restrict__ lwp,
                 ushort* __restrict__ yhb, ushort* __restrict__ ylb)
{
    __shared__ ushort SMEM[16384];   // Kh|Kl|Vh|Vl (4096 ush each); epi: Ot f32
    __shared__ float mbias[64];
    ushort* Kh = SMEM;
    ushort* Kl = SMEM + 4096;
    ushort* Vh = SMEM + 8192;
    ushort* Vl = SMEM + 12288;
    const int t = threadIdx.x, lane = t & 63, w = t >> 6;
    const int g = lane >> 4, ln = lane & 15;
    const int qt = blockIdx.x, bh = blockIdx.y;
    const int b = bh >> 4, h = bh & 15, kvh = h >> 2;
    const int LW = lwp[0];
    const int q0 = qt*64;
    const ushort* Qhp = qhb + ((size_t)(b*16+h)*SS + q0)*64;
    const ushort* Qlp = qlb + ((size_t)(b*16+h)*SS + q0)*64;
    const ushort* Khp = khb + ((size_t)(b*4+kvh)*SS)*64;
    const ushort* Klp = klb + ((size_t)(b*4+kvh)*SS)*64;
    const ushort* Vhp = vhT + (size_t)(b*4+kvh)*64*SS;
    const ushort* Vlp = vlT + (size_t)(b*4+kvh)*64*SS;

    // Q frags direct from global: row = 16w+ln, 8 consecutive d at (4s+g)*8
    v8s qfh[2], qfl[2];
    {
        int row = 16*w + ln;
#pragma unroll
        for (int s=0;s<2;s++){
            qfh[s] = *(const v8s*)(Qhp + (size_t)row*64 + (4*s+g)*8);
            qfl[s] = *(const v8s*)(Qlp + (size_t)row*64 + (4*s+g)*8);
        }
    }
    const int qg = q0 + 16*w + ln;
    const int keyk = (ln&3) ^ ((ln>>2)<<1);
    float m_r = -1e30f, l_r = 0.f;
    const v4f vzero = {0.f,0.f,0.f,0.f};
    v4f o[4];
#pragma unroll
    for (int dt=0;dt<4;dt++) o[dt] = vzero;

    const int sr = t>>3, sc = t&7;
    int lo = q0 - LW + 1; if (lo < 0) lo = 0;
    const int kt0 = lo>>6;
    const float SC2 = 0.125f * 1.44269504088896f;   // fold log2e: exp2 softmax

    // ---- reg-staged prefetch: tile kt0 ----
    uint4 rkh[2], rkl[2], rvh[2], rvl[2];
    int mb = 0;
#pragma unroll
    for (int p2=0;p2<2;p2++){
        int rr = sr + 32*p2;
        rkh[p2] = *(const uint4*)(Khp + (size_t)(kt0*64+rr)*64 + sc*8);
        rkl[p2] = *(const uint4*)(Klp + (size_t)(kt0*64+rr)*64 + sc*8);
        rvh[p2] = *(const uint4*)(Vhp + (size_t)rr*SS + kt0*64 + sc*8);
        rvl[p2] = *(const uint4*)(Vlp + (size_t)rr*SS + kt0*64 + sc*8);
    }
    if (t < 64) mb = amask[(b<<11) + kt0*64 + t];

    for (int kt = kt0; kt <= qt; kt++){
        int k0 = kt*64;
        __syncthreads();          // prev tile's LDS consumers done
        // write staged regs -> LDS
#pragma unroll
        for (int p2=0;p2<2;p2++){
            int rr = sr + 32*p2;
            int kkey = (rr&3) ^ (((rr>>3)&3)<<1);
            *(uint4*)&Kh[rr*64 + ((sc ^ kkey)<<3)] = rkh[p2];
            *(uint4*)&Kl[rr*64 + ((sc ^ kkey)<<3)] = rkl[p2];
            *(uint4*)&Vh[rr*64 + ((sc ^ (rr&7))<<3)] = rvh[p2];
            *(uint4*)&Vl[rr*64 + ((sc ^ (rr&7))<<3)] = rvl[p2];
        }
        if (t < 64) mbias[t] = mb ? 0.f : -3.0e38f;
        // issue next-tile loads (in flight during compute)
        if (kt < qt){
#pragma unroll
            for (int p2=0;p2<2;p2++){
                int rr = sr + 32*p2;
                rkh[p2] = *(const uint4*)(Khp + (size_t)(k0+64+rr)*64 + sc*8);
                rkl[p2] = *(const uint4*)(Klp + (size_t)(k0+64+rr)*64 + sc*8);
                rvh[p2] = *(const uint4*)(Vhp + (size_t)rr*SS + k0+64 + sc*8);
                rvl[p2] = *(const uint4*)(Vlp + (size_t)rr*SS + k0+64 + sc*8);
            }
            if (t < 64) mb = amask[(b<<11) + k0+64 + t];
        }
        __syncthreads();          // this tile's LDS ready

        // S^T = K . Q^T (3-term split), permuted k-rows
        float p[4][4];
#pragma unroll
        for (int tau=0;tau<4;tau++){
            v4f sa = vzero;
            int krow = 32*(tau&1) + 8*(ln>>2) + 4*(tau>>1) + (ln&3);
#pragma unroll
            for (int s=0;s<2;s++){
                int off = krow*64 + (((4*s+g) ^ keyk)<<3);
                v8s afh = *(v8s*)&Kh[off];
                v8s afl = *(v8s*)&Kl[off];
                sa = MFMA16(afh, qfh[s], sa, 0,0,0);
                sa = MFMA16(afh, qfl[s], sa, 0,0,0);
                sa = MFMA16(afl, qfh[s], sa, 0,0,0);
            }
#pragma unroll
            for (int r=0;r<4;r++) p[tau][r] = sa[r];
        }

        // mask (edge tiles only) + online softmax in base-2 domain
        const bool edge = (kt == qt) || (k0 < q0 + 64 - LW);
        float pmax = -3.0e38f;
#pragma unroll
        for (int tau=0;tau<4;tau++)
#pragma unroll
            for (int r=0;r<4;r++){
                int kk  = 32*(tau&1) + 8*g + 4*(tau>>1) + r;
                float scv = p[tau][r]*SC2 + mbias[kk];
                if (edge){
                    int kgl = k0 + kk;
                    bool ok = (kgl <= qg) && (qg - kgl < LW);
                    scv = ok ? scv : -3.0e38f;
                }
                p[tau][r] = scv;
                pmax = fmaxf(pmax, scv);
            }
        pmax = fmaxf(pmax, __shfl_xor(pmax,16));
        pmax = fmaxf(pmax, __shfl_xor(pmax,32));
        bool defer = __all(pmax <= m_r + 8.0f);   // T13: skip rescale
        float mnew = defer ? m_r : fmaxf(m_r, pmax);
        float ls = 0.f;
#pragma unroll
        for (int tau=0;tau<4;tau++)
#pragma unroll
            for (int r=0;r<4;r++){
                float e = exp2f(p[tau][r] - mnew);
                p[tau][r] = e; ls += e;
            }
        ls += __shfl_xor(ls,16); ls += __shfl_xor(ls,32);
        if (!defer){
            float al = exp2f(m_r - mnew);
            l_r = l_r*al;
#pragma unroll
            for (int dt=0;dt<4;dt++) o[dt] = o[dt]*al;
            m_r = mnew;
        }
        l_r += ls;

        // pack split P (per-lane): B-frag elem e of K-step s <- p[2*(e>>2)+s][e&3]
        v8s pbh[2], pbl[2];
#pragma unroll
        for (int s=0;s<2;s++){
            v8s ph, pl;
#pragma unroll
            for (int e=0;e<8;e++){
                float val = p[2*(e>>2)+s][e&3];
                ushort hh = f2bf(val);
                ph[e] = (short)hh;
                pl[e] = (short)f2bf(val - bf2f(hh));
            }
            pbh[s]=ph; pbl[s]=pl;
        }
        // O^T += V^T . P^T (3-term split)
#pragma unroll
        for (int dt=0;dt<4;dt++){
            int drow = 16*dt + ln;
#pragma unroll
            for (int s=0;s<2;s++){
                int off = drow*64 + (((4*s+g) ^ (ln&7))<<3);
                v8s vfh = *(v8s*)&Vh[off];
                v8s vfl = *(v8s*)&Vl[off];
                o[dt] = MFMA16(vfh, pbh[s], o[dt], 0,0,0);
                o[dt] = MFMA16(vfh, pbl[s], o[dt], 0,0,0);
                o[dt] = MFMA16(vfl, pbh[s], o[dt], 0,0,0);
            }
        }
    }

    // epilogue: O^T -> LDS transpose (stride 68) -> coalesced split-bf16 y rows
    __syncthreads();
    float inv = (l_r > 0.f) ? (1.0f / l_r) : 0.f;
    float* Ot = (float*)SMEM;
#pragma unroll
    for (int dt=0;dt<4;dt++)
#pragma unroll
        for (int r=0;r<4;r++){
            int d = 16*dt + 4*g + r;
            Ot[d*68 + 16*w + ln] = o[dt][r]*inv;
        }
    __syncthreads();
    {
        int q = t>>2, dp = t&3;
        ushort th[16], tl[16];
#pragma unroll
        for (int i=0;i<16;i++){
            float val = Ot[(dp*16+i)*68 + q];
            ushort hh = f2bf(val);
            th[i] = hh;
            tl[i] = f2bf(val - bf2f(hh));
        }
        size_t doff = (size_t)(b*SS + q0 + q)*EE + h*64 + dp*16;
        *(uint4*)(yhb + doff)     = *(uint4*)&th[0];
        *(uint4*)(yhb + doff + 8) = *(uint4*)&th[8];
        *(uint4*)(ylb + doff)     = *(uint4*)&tl[0];
        *(uint4*)(ylb + doff + 8) = *(uint4*)&tl[8];
    }
}

// ---------------------------------------------------------------------------
// Output projection: split-bf16 MFMA GEMM, out fp32.  grid (16, 32), block 256
// PRE=true: B staged from pre-split Wph/Wpl.
// ---------------------------------------------------------------------------
template<bool PRE>
__global__ __launch_bounds__(256)
void proj_kernel(const ushort* __restrict__ yhb, const ushort* __restrict__ ylb,
                 const float* __restrict__ Wp, const ushort* __restrict__ Wph,
                 const ushort* __restrict__ Wpl, float* __restrict__ out)
{
    __shared__ ushort Ayh[128*64];   // 16 KB
    __shared__ ushort Ayl[128*64];   // 16 KB
    __shared__ ushort Bh[64*64];     //  8 KB
    __shared__ ushort Bl[64*64];     //  8 KB
    const int t = threadIdx.x;
    const int lane = t & 63, w = t >> 6;
    const int g = lane >> 4, ln = lane & 15;
    const int nt = blockIdx.x, mt = blockIdx.y;
    const v4f vzero = {0.f,0.f,0.f,0.f};
    v4f acc[2][4];
#pragma unroll
    for (int m=0;m<2;m++)
#pragma unroll
        for (int j=0;j<4;j++) acc[m][j] = vzero;

    const int sr = t>>3, sc = t&7;
    for (int kt = 0; kt < EE; kt += 64){
#pragma unroll
        for (int p2=0;p2<4;p2++){
            int rr = sr + 32*p2;
            int off = rr*64 + ((sc ^ (rr&7))<<3);
            *(uint4*)&Ayh[off] = *(const uint4*)(yhb + (size_t)(mt*128+rr)*EE + kt + sc*8);
            *(uint4*)&Ayl[off] = *(const uint4*)(ylb + (size_t)(mt*128+rr)*EE + kt + sc*8);
        }
#pragma unroll
        for (int p2=0;p2<2;p2++){
            int rr = sr + 32*p2;
            int off = rr*64 + ((sc ^ (rr&7))<<3);
            if (PRE){
                *(uint4*)&Bh[off] = *(const uint4*)(Wph + (size_t)(nt*64+rr)*EE + kt + sc*8);
                *(uint4*)&Bl[off] = *(const uint4*)(Wpl + (size_t)(nt*64+rr)*EE + kt + sc*8);
            } else {
                uint4 H,L; split8(Wp + (size_t)(nt*64+rr)*EE + kt + sc*8, H, L);
                *(uint4*)&Bh[off] = H; *(uint4*)&Bl[off] = L;
            }
        }
        __syncthreads();
        v8s ah[2][2], al[2][2], bh[4][2], bl[4][2];
#pragma unroll
        for (int m=0;m<2;m++){
            int row = 32*w + 16*m + ln;
#pragma unroll
            for (int s=0;s<2;s++){
                int off = row*64 + (((4*s+g) ^ (row&7))<<3);
                ah[m][s] = *(v8s*)&Ayh[off];
                al[m][s] = *(v8s*)&Ayl[off];
            }
        }
#pragma unroll
        for (int j=0;j<4;j++){
            int row = 16*j + ln;
#pragma unroll
            for (int s=0;s<2;s++){
                int off = row*64 + (((4*s+g) ^ (row&7))<<3);
                bh[j][s] = *(v8s*)&Bh[off];
                bl[j][s] = *(v8s*)&Bl[off];
            }
        }
#pragma unroll
        for (int m=0;m<2;m++)
#pragma unroll
            for (int j=0;j<4;j++)
#pragma unroll
                for (int s=0;s<2;s++){
                    acc[m][j] = MFMA16(ah[m][s], bh[j][s], acc[m][j], 0,0,0);
                    acc[m][j] = MFMA16(ah[m][s], bl[j][s], acc[m][j], 0,0,0);
                    acc[m][j] = MFMA16(al[m][s], bh[j][s], acc[m][j], 0,0,0);
                }
        __syncthreads();
    }

#pragma unroll
    for (int m=0;m<2;m++)
#pragma unroll
        for (int r=0;r<4;r++){
            size_t grow = (size_t)mt*128 + 32*w + 16*m + 4*g + r;
#pragma unroll
            for (int j=0;j<4;j++)
                out[grow*EE + nt*64 + 16*j + ln] = acc[m][j][r];
        }
}

// ---------------------------------------------------------------------------
extern "C" void kernel_launch(void* const* d_in, const int* in_sizes, int n_in,
                              void* d_out, int out_size, void* d_ws, size_t ws_size,
                              hipStream_t stream)
{
    (void)in_sizes; (void)n_in; (void)out_size;
    const float* x     = (const float*)d_in[0];
    const float* ve    = (const float*)d_in[1];
    const float* cosb  = (const float*)d_in[2];
    const float* sinb  = (const float*)d_in[3];
    const float* Wq    = (const float*)d_in[4];
    const float* Wk    = (const float*)d_in[5];
    const float* Wv    = (const float*)d_in[6];
    const float* Wp    = (const float*)d_in[7];
    const float* Wg    = (const float*)d_in[8];
    const int*   amask = (const int*)d_in[9];
    const int*   lw    = (const int*)d_in[10];
    float* out = (float*)d_out;
    char* ws = (char*)d_ws;

    if (ws_size >= (size_t)(50u<<20)){
        // ---- pre-split path (50 MB) ----
        ushort* xh  = (ushort*)(ws);                 // 8 MB  x hi   -> later y hi
        ushort* xl  = (ushort*)(ws + ( 8u<<20));     // 8 MB  x lo   -> later y lo
        ushort* Wch = (ushort*)(ws + (16u<<20));     // 3 MB  [Wq;Wk;Wv] hi
        ushort* Wcl = (ushort*)(ws + (19u<<20));     // 3 MB  [Wq;Wk;Wv] lo
        ushort* Wph = (ushort*)(ws + (22u<<20));     // 2 MB  Wp hi
        ushort* Wpl = (ushort*)(ws + (24u<<20));     // 2 MB  Wp lo
        ushort* qhb = (ushort*)(ws + (26u<<20));     // 8 MB  q hi [b*16+h][s][64]
        ushort* qlb = (ushort*)(ws + (34u<<20));     // 8 MB  q lo
        ushort* khb = (ushort*)(ws + (42u<<20));     // 2 MB  k hi [b*4+kvh][s][64]
        ushort* klb = (ushort*)(ws + (44u<<20));     // 2 MB  k lo
        ushort* vhT = (ushort*)(ws + (46u<<20));     // 2 MB  v^T hi [b*4+kvh][64][s]
        ushort* vlT = (ushort*)(ws + (48u<<20));     // 2 MB  v^T lo
        ushort* yhb = xh;                            // reuse (x-splits dead after qkv)
        ushort* ylb = xl;

        split_all<<<3328, 256, 0, stream>>>(x, Wq, Wk, Wv, Wp,
                                            xh, xl, Wch, Wcl, Wph, Wpl);
        qkv_kernel<true><<<dim3(24,32), 256, 0, stream>>>(x, ve, Wq, Wk, Wv, Wg,
                xh, xl, Wch, Wcl, cosb, sinb, qhb, qlb, khb, klb, vhT, vlT);
        attn_kernel<<<dim3(32,32), 256, 0, stream>>>(qhb, qlb, khb, klb, vhT, vlT,
                amask, lw, yhb, ylb);
        proj_kernel<true><<<dim3(16,32), 256, 0, stream>>>(yhb, ylb, Wp, Wph, Wpl, out);
    } else {
        // ---- fallback: split-on-the-fly path (40 MB) ----
        ushort* qhb = (ushort*)(ws);                 // 8 MB
        ushort* qlb = (ushort*)(ws + ( 8u<<20));     // 8 MB
        ushort* khb = (ushort*)(ws + (16u<<20));     // 2 MB
        ushort* klb = (ushort*)(ws + (18u<<20));     // 2 MB
        ushort* vhT = (ushort*)(ws + (20u<<20));     // 2 MB
        ushort* vlT = (ushort*)(ws + (22u<<20));     // 2 MB
        ushort* yhb = (ushort*)(ws + (24u<<20));     // 8 MB
        ushort* ylb = (ushort*)(ws + (32u<<20));     // 8 MB

        qkv_kernel<false><<<dim3(24,32), 256, 0, stream>>>(x, ve, Wq, Wk, Wv, Wg,
                nullptr, nullptr, nullptr, nullptr, cosb, sinb,
                qhb, qlb, khb, klb, vhT, vlT);
        attn_kernel<<<dim3(32,32), 256, 0, stream>>>(qhb, qlb, khb, klb, vhT, vlT,
                amask, lw, yhb, ylb);
        proj_kernel<false><<<dim3(16,32), 256, 0, stream>>>(yhb, ylb, Wp, nullptr, nullptr, out);
    }
}